// Round 1
// baseline (374.463 us; speedup 1.0000x reference)
//
#include <hip/hip_runtime.h>

#define DD 2048   // D = 2*hidden
#define BB 16     // batch
#define SS 2048   // seq

// Kernel 1: altered[b, d] = bias[d] + sum_k state[b,k] * W[d,k]
// One block per output column d. Each thread strides over W[d,:] in float4,
// keeping one accumulator per batch row (state is 128 KiB -> L2 resident).
__global__ __launch_bounds__(256) void linear_kernel(
    const float* __restrict__ state,   // [B, D]
    const float* __restrict__ W,       // [D, D] row-major, W[d, k]
    const float* __restrict__ bias,    // [D]
    float* __restrict__ altered)       // [B, D]
{
    const int d    = blockIdx.x;
    const int tid  = threadIdx.x;
    const int lane = tid & 63;
    const int wave = tid >> 6;

    const float4* W4 = (const float4*)(W + (size_t)d * DD);  // 512 float4
    const float4* S4 = (const float4*)state;                 // B * 512 float4

    float acc[BB];
#pragma unroll
    for (int b = 0; b < BB; ++b) acc[b] = 0.f;

#pragma unroll
    for (int it = 0; it < 2; ++it) {
        const int k4 = tid + it * 256;           // 0..511
        const float4 w = W4[k4];
#pragma unroll
        for (int b = 0; b < BB; ++b) {
            const float4 s = S4[b * 512 + k4];
            acc[b] += w.x * s.x + w.y * s.y + w.z * s.z + w.w * s.w;
        }
    }

    // wave-level butterfly reduction of each of the 16 accumulators
#pragma unroll
    for (int b = 0; b < BB; ++b) {
#pragma unroll
        for (int off = 32; off > 0; off >>= 1)
            acc[b] += __shfl_xor(acc[b], off, 64);
    }

    __shared__ float red[4][BB];
    if (lane == 0) {
#pragma unroll
        for (int b = 0; b < BB; ++b) red[wave][b] = acc[b];
    }
    __syncthreads();
    if (tid < BB) {
        const float v = red[0][tid] + red[1][tid] + red[2][tid] + red[3][tid]
                      + bias[d];
        altered[tid * DD + d] = v;
    }
}

// Kernel 2: out[b, s] = sum_d altered[b,d] * enc[s,b,d]
// One 64-lane wave per (s,b) output. enc[s,b,:] is a contiguous 8 KiB run at
// offset wid*2048 where wid = s*B + b -> float4 loads are fully coalesced and
// consecutive waves stream consecutive memory.
__global__ __launch_bounds__(256) void attend_kernel(
    const float* __restrict__ enc,      // [S, B, D]
    const float* __restrict__ altered,  // [B, D]
    float* __restrict__ out)            // [B, S]
{
    const int tid  = threadIdx.x;
    const int lane = tid & 63;
    const int wid  = blockIdx.x * 4 + (tid >> 6);  // global wave id = s*B + b
    const int b    = wid & (BB - 1);
    const int s    = wid >> 4;

    const float4* E4 = (const float4*)enc;       // chunk [wid*512, wid*512+512)
    const float4* A4 = (const float4*)altered;   // row b: [b*512, b*512+512)

    float acc = 0.f;
#pragma unroll
    for (int j = 0; j < 8; ++j) {
        const int o = j * 64 + lane;             // 0..511
        const float4 e = E4[(size_t)wid * 512 + o];
        const float4 a = A4[b * 512 + o];
        acc += e.x * a.x + e.y * a.y + e.z * a.z + e.w * a.w;
    }

#pragma unroll
    for (int off = 32; off > 0; off >>= 1)
        acc += __shfl_xor(acc, off, 64);

    if (lane == 0) out[b * SS + s] = acc;
}

extern "C" void kernel_launch(void* const* d_in, const int* in_sizes, int n_in,
                              void* d_out, int out_size, void* d_ws, size_t ws_size,
                              hipStream_t stream) {
    const float* enc   = (const float*)d_in[0];  // [S, B, D]
    const float* state = (const float*)d_in[1];  // [B, D]
    const float* W     = (const float*)d_in[2];  // [D, D]
    const float* bias  = (const float*)d_in[3];  // [D]
    float*       out   = (float*)d_out;          // [B, S]

    float* altered = (float*)d_ws;               // [B, D] = 128 KiB scratch

    linear_kernel<<<DD, 256, 0, stream>>>(state, W, bias, altered);

    const int nwaves  = SS * BB;                 // one wave per output
    const int nblocks = nwaves / 4;              // 4 waves per 256-thr block
    attend_kernel<<<nblocks, 256, 0, stream>>>(enc, altered, out);
}

// Round 3
// 356.750 us; speedup vs baseline: 1.0497x; 1.0497x over previous
//
#include <hip/hip_runtime.h>

#define DD 2048   // D = 2*hidden
#define BB 16     // batch
#define SS 2048   // seq

// native vector type: accepted by __builtin_nontemporal_load (HIP's float4
// class type is not)
typedef float f4 __attribute__((ext_vector_type(4)));

// Kernel 1: altered[b, d] = bias[d] + sum_k state[b,k] * W[d,k]
// One block per output column d. W row streamed once (nontemporal);
// state (128 KiB) stays L2-resident and is re-read by every block.
__global__ __launch_bounds__(256) void linear_kernel(
    const float* __restrict__ state,   // [B, D]
    const float* __restrict__ W,       // [D, D] row-major, W[d, k]
    const float* __restrict__ bias,    // [D]
    float* __restrict__ altered)       // [B, D]
{
    const int d    = blockIdx.x;
    const int tid  = threadIdx.x;
    const int lane = tid & 63;
    const int wave = tid >> 6;

    const f4* W4 = (const f4*)(W + (size_t)d * DD);  // 512 f4
    const f4* S4 = (const f4*)state;                 // B * 512 f4

    float acc[BB];
#pragma unroll
    for (int b = 0; b < BB; ++b) acc[b] = 0.f;

#pragma unroll
    for (int it = 0; it < 2; ++it) {
        const int k4 = tid + it * 256;           // 0..511
        const f4 w = __builtin_nontemporal_load(&W4[k4]);
#pragma unroll
        for (int b = 0; b < BB; ++b) {
            const f4 s = S4[b * 512 + k4];
            acc[b] += w.x * s.x + w.y * s.y + w.z * s.z + w.w * s.w;
        }
    }

    // wave-level butterfly reduction of each of the 16 accumulators
#pragma unroll
    for (int b = 0; b < BB; ++b) {
#pragma unroll
        for (int off = 32; off > 0; off >>= 1)
            acc[b] += __shfl_xor(acc[b], off, 64);
    }

    __shared__ float red[4][BB];
    if (lane == 0) {
#pragma unroll
        for (int b = 0; b < BB; ++b) red[wave][b] = acc[b];
    }
    __syncthreads();
    if (tid < BB) {
        const float v = red[0][tid] + red[1][tid] + red[2][tid] + red[3][tid]
                      + bias[d];
        altered[tid * DD + d] = v;
    }
}

// Kernel 2: out[b, s] = sum_d altered[b,d] * enc[s,b,d]
// 8192 persistent waves; wave wv handles wid = wv, wv+8192, wv+16384, wv+24576.
// Since 8192 % 16 == 0, b = wv & 15 is constant per wave -> the altered[b,:]
// row is loaded ONCE into 32 VGPRs and reused for all 4 s-iterations.
// enc chunks are contiguous 8 KiB runs, nontemporal (zero reuse).
__global__ __launch_bounds__(256) void attend_kernel(
    const float* __restrict__ enc,      // [S, B, D]
    const float* __restrict__ altered,  // [B, D]
    float* __restrict__ out)            // [B, S]
{
    const int lane = threadIdx.x & 63;
    const int wv   = blockIdx.x * 4 + (threadIdx.x >> 6);  // 0..8191
    const int b    = wv & (BB - 1);

    const f4* A4 = (const f4*)altered + (size_t)b * 512;
    f4 a[8];
#pragma unroll
    for (int j = 0; j < 8; ++j) a[j] = A4[j * 64 + lane];

    const f4* E4 = (const f4*)enc;
#pragma unroll
    for (int it = 0; it < 4; ++it) {
        const int wid = wv + it * 8192;          // s = wid >> 4, same b
        f4 e[8];
#pragma unroll
        for (int j = 0; j < 8; ++j)
            e[j] = __builtin_nontemporal_load(&E4[(size_t)wid * 512 + j * 64 + lane]);

        float acc = 0.f;
#pragma unroll
        for (int j = 0; j < 8; ++j)
            acc += e[j].x * a[j].x + e[j].y * a[j].y
                 + e[j].z * a[j].z + e[j].w * a[j].w;

#pragma unroll
        for (int off = 32; off > 0; off >>= 1)
            acc += __shfl_xor(acc, off, 64);

        if (lane == 0) out[b * SS + (wid >> 4)] = acc;
    }
}

extern "C" void kernel_launch(void* const* d_in, const int* in_sizes, int n_in,
                              void* d_out, int out_size, void* d_ws, size_t ws_size,
                              hipStream_t stream) {
    const float* enc   = (const float*)d_in[0];  // [S, B, D]
    const float* state = (const float*)d_in[1];  // [B, D]
    const float* W     = (const float*)d_in[2];  // [D, D]
    const float* bias  = (const float*)d_in[3];  // [D]
    float*       out   = (float*)d_out;          // [B, S]

    float* altered = (float*)d_ws;               // [B, D] = 128 KiB scratch

    linear_kernel<<<DD, 256, 0, stream>>>(state, W, bias, altered);

    attend_kernel<<<2048, 256, 0, stream>>>(enc, altered, out);
}